// Round 1
// baseline (125.695 us; speedup 1.0000x reference)
//
#include <hip/hip_runtime.h>
#include <math.h>

#define PI_F 3.14159265358979323846f

typedef __attribute__((ext_vector_type(8))) short bh8;    // 8 bf16 in 4 VGPRs
typedef __attribute__((ext_vector_type(4))) float f32x4;  // MFMA accumulator

// ---- sizes ----
#define LAG1 12      // LAG-1
#define BB   32      // batch
#define NN   1200
#define MROWS 1152   // 3 * 12 * 32
#define KPAD 1216    // 1200 padded to 38*32
#define NPAD 1216

__device__ __forceinline__ unsigned short f2bf(float f) {
    unsigned int u = __float_as_uint(f);
    u = (u + 0x7fffu + ((u >> 16) & 1u)) >> 16;
    return (unsigned short)u;
}

__device__ __forceinline__ float gamma_fn_dev(float x) {
    if (x > 0.0f) return expf(lgammaf(x));
    return PI_F / (sinf(PI_F * x) * expf(lgammaf(1.0f - x)));
}

// ---- per-lag coefficients: coef[0..11]=e0=2*3^fract, [12..23]=c2, [24..35]=1/belta
__global__ void prep_coef(const float* __restrict__ alpha, const float* __restrict__ fract,
                          float* __restrict__ coef) {
    int lag = threadIdx.x;
    if (lag >= LAG1) return;
    float a = alpha[lag], f = fract[lag];
    float ga1 = expf(lgammaf(a + 1.0f));
    float belta = 0.0f;
    const float gk[4] = {1.0f, 1.0f, 2.0f, 6.0f};
    #pragma unroll
    for (int kk = 0; kk < 4; kk++)
        belta += ga1 / (gk[kk] * gamma_fn_dev(a - (float)kk + 1.0f));
    float c2 = ga1 / (6.0f * gamma_fn_dev(a - 2.0f));
    coef[lag]      = 2.0f * powf(3.0f, f);
    coef[12 + lag] = c2;
    coef[24 + lag] = 1.0f / belta;
}

// ---- build stacked X (MROWS x KPAD) bf16:
// rows [0,384):   A[lag,b,i]              (r = lag*32+b)
// rows [384,768): train_init[b,i,lag,1]   (-> A_N_OLD path)
// rows [768,1152):train_init[b,i,lag+1,1] (-> A_0_NEW path)
__global__ void prep_X(const float* __restrict__ A, const float* __restrict__ TI,
                       unsigned short* __restrict__ X) {
    int idx = blockIdx.x * 256 + threadIdx.x;
    if (idx >= MROWS * KPAD) return;
    int r = idx / KPAD, k = idx - r * KPAD;
    float v = 0.0f;
    if (k < NN) {
        int g = r / 384, rr = r - g * 384;
        int lag = rr >> 5, b = rr & 31;
        if (g == 0) {
            v = A[rr * NN + k];
        } else {
            int lg = (g == 1) ? lag : (lag + 1);
            v = TI[((b * NN + k) * 13 + lg) * 2 + 1];
        }
    }
    X[idx] = f2bf(v);
}

// ---- WT[j*1216 + i] = bf16(WW[i*1200 + j]), zero-padded; LDS-tiled transpose
__global__ void prep_WT(const float* __restrict__ WW, unsigned short* __restrict__ WT) {
    __shared__ float tile[32][33];
    int i0 = blockIdx.y * 32, j0 = blockIdx.x * 32;
    int tx = threadIdx.x, ty = threadIdx.y;   // 32 x 8
    #pragma unroll
    for (int s = 0; s < 32; s += 8) {
        int i = i0 + ty + s, j = j0 + tx;
        tile[ty + s][tx] = (i < NN && j < NN) ? WW[i * NN + j] : 0.0f;
    }
    __syncthreads();
    #pragma unroll
    for (int s = 0; s < 32; s += 8) {
        int j = j0 + ty + s, i = i0 + tx;
        WT[j * NPAD + i] = f2bf(tile[tx][ty + s]);
    }
}

// ---- GEMM: T[m,n] = tanh(-sum_k X[m,k]*WT[n,k]); 64x64 tile, 4 waves, 16x16x32 bf16
__global__ __launch_bounds__(256) void gemm_kernel(const unsigned short* __restrict__ X,
                                                   const unsigned short* __restrict__ WT,
                                                   float* __restrict__ T) {
    __shared__ unsigned short As[64 * 40];   // +8 pad: breaks bank conflicts
    __shared__ unsigned short Bs[64 * 40];
    const int tid  = threadIdx.x;
    const int bm   = blockIdx.x, bn = blockIdx.y;
    const int wave = tid >> 6, lane = tid & 63;
    const int wm   = (wave >> 1) * 32, wn = (wave & 1) * 32;
    const int lrow = tid >> 2;            // 0..63
    const int lcol = (tid & 3) * 8;       // 0,8,16,24
    const int l15  = lane & 15;
    const int kq   = (lane >> 4) * 8;

    const unsigned short* gA = X  + (bm * 64 + lrow) * KPAD + lcol;
    const unsigned short* gB = WT + (bn * 64 + lrow) * NPAD + lcol;

    f32x4 acc[2][2] = {};

    for (int k0 = 0; k0 < KPAD; k0 += 32) {
        __syncthreads();
        *(int4*)&As[lrow * 40 + lcol] = *(const int4*)(gA + k0);
        *(int4*)&Bs[lrow * 40 + lcol] = *(const int4*)(gB + k0);
        __syncthreads();
        bh8 a0 = *(const bh8*)&As[(wm +      l15) * 40 + kq];
        bh8 a1 = *(const bh8*)&As[(wm + 16 + l15) * 40 + kq];
        bh8 b0 = *(const bh8*)&Bs[(wn +      l15) * 40 + kq];
        bh8 b1 = *(const bh8*)&Bs[(wn + 16 + l15) * 40 + kq];
        acc[0][0] = __builtin_amdgcn_mfma_f32_16x16x32_bf16(a0, b0, acc[0][0], 0, 0, 0);
        acc[0][1] = __builtin_amdgcn_mfma_f32_16x16x32_bf16(a0, b1, acc[0][1], 0, 0, 0);
        acc[1][0] = __builtin_amdgcn_mfma_f32_16x16x32_bf16(a1, b0, acc[1][0], 0, 0, 0);
        acc[1][1] = __builtin_amdgcn_mfma_f32_16x16x32_bf16(a1, b1, acc[1][1], 0, 0, 0);
    }

    // C/D layout: col = lane&15, row = (lane>>4)*4 + reg
    #pragma unroll
    for (int fm = 0; fm < 2; fm++) {
        #pragma unroll
        for (int fn = 0; fn < 2; fn++) {
            #pragma unroll
            for (int r = 0; r < 4; r++) {
                int gm = bm * 64 + wm + fm * 16 + (lane >> 4) * 4 + r;
                int gn = bn * 64 + wn + fn * 16 + l15;
                if (gn < NN) T[gm * NN + gn] = tanhf(-acc[fm][fn][r]);
            }
        }
    }
}

// ---- epilogue: out[b,lag,j] = lambd*ib*(e0*Tout + 3*l*(T0 + c2*TN))
__global__ void epilogue(const float* __restrict__ T, const float* __restrict__ lambd,
                         const float* __restrict__ l, const float* __restrict__ coef,
                         float* __restrict__ out) {
    int idx = blockIdx.x * 256 + threadIdx.x;
    if (idx >= BB * LAG1 * NN) return;
    int j = idx % NN;
    int t = idx / NN;
    int lag = t % LAG1, b = t / LAG1;
    int r = lag * 32 + b;
    float Tout = T[r * NN + j];
    float TN   = T[(384 + r) * NN + j];
    float T0   = T[(768 + r) * NN + j];
    int jm = j % 200;
    float lv  = l[lag * 200 + jm];
    float lam = lambd[lag * 200 + jm];
    float e0 = coef[lag], c2 = coef[12 + lag], ib = coef[24 + lag];
    out[idx] = lam * ib * (e0 * Tout + 3.0f * lv * (T0 + c2 * TN));
}

extern "C" void kernel_launch(void* const* d_in, const int* in_sizes, int n_in,
                              void* d_out, int out_size, void* d_ws, size_t ws_size,
                              hipStream_t stream) {
    const float* A     = (const float*)d_in[0];
    const float* WW    = (const float*)d_in[1];
    const float* TI    = (const float*)d_in[2];
    const float* alpha = (const float*)d_in[3];
    const float* fract = (const float*)d_in[4];
    const float* lambd = (const float*)d_in[5];
    const float* l     = (const float*)d_in[6];
    float* out = (float*)d_out;

    unsigned short* X  = (unsigned short*)d_ws;                 // 1152*1216 bf16
    unsigned short* WT = X + MROWS * KPAD;                      // 1216*1216 bf16
    float* T    = (float*)(WT + NPAD * NPAD);                   // 1152*1200 f32
    float* coef = T + MROWS * NN;                               // 36 f32

    prep_coef<<<1, 64, 0, stream>>>(alpha, fract, coef);
    prep_X<<<(MROWS * KPAD + 255) / 256, 256, 0, stream>>>(A, TI, X);
    prep_WT<<<dim3(38, 38), dim3(32, 8), 0, stream>>>(WW, WT);
    gemm_kernel<<<dim3(18, 19), 256, 0, stream>>>(X, WT, T);
    epilogue<<<(BB * LAG1 * NN + 255) / 256, 256, 0, stream>>>(T, lambd, l, coef, out);
}